// Round 4
// baseline (393.293 us; speedup 1.0000x reference)
//
#include <hip/hip_runtime.h>
#include <hip/hip_bf16.h>

// E=32 experts, H=1024 hidden, F=512 ffn, T=1024 tokens, K=8 top-k.
#define NE     32
#define HD     1024
#define FF     512
#define NT     1024
#define TOPK   8
#define NPAIR  (NT * TOPK)      // 8192 routed (token,k) rows
#define MAXT2  96               // max 128-row tiles: 8192/128 + 32

typedef __attribute__((ext_vector_type(8))) short  bf16x8;
typedef __attribute__((ext_vector_type(4))) float  f32x4;

__device__ __forceinline__ unsigned short f2bf_rne(float f) {
    unsigned u = __float_as_uint(f);
    u += 0x7FFFu + ((u >> 16) & 1u);
    return (unsigned short)(u >> 16);
}
__device__ __forceinline__ unsigned pk2(float x, float y) {
    __hip_bfloat162 h = __float22bfloat162_rn(float2{x, y});
    union { __hip_bfloat162 h; unsigned u; } c;
    c.h = h;
    return c.u;
}
__device__ __forceinline__ uint4 pk8v(float4 a, float4 b) {
    uint4 r;
    r.x = pk2(a.x, a.y); r.y = pk2(a.z, a.w);
    r.z = pk2(b.x, b.y); r.w = pk2(b.z, b.w);
    return r;
}
#define MFMA16(a, b, c) __builtin_amdgcn_mfma_f32_16x16x32_bf16(a, b, c, 0, 0, 0)

// ---------------- workspace layout ----------------
// meta ints: [0]=numt, [1..33]=offsets, [64..159]=tile_e, [160..255]=tile_m,
//            [256..]=tok_list(8192), w_list @ +8448, posmap @ +16640
// bytes: A_bf @128K (8MB bf16) | O_rows @128K+8M (32MB f32)

__global__ __launch_bounds__(1024) void k_route(const int* __restrict__ idx,
                                                const float* __restrict__ tkw,
                                                int* __restrict__ meta) {
    __shared__ int sc[NE], scur[NE], soff[NE + 1];
    __shared__ int ste[MAXT2], stm[MAXT2], snt;
    int tid = threadIdx.x;                      // tid == token
    if (tid < NE) { sc[tid] = 0; scur[tid] = 0; }
    __syncthreads();
    int e8[TOPK];
#pragma unroll
    for (int j = 0; j < TOPK; j++) { e8[j] = idx[tid * TOPK + j]; atomicAdd(&sc[e8[j]], 1); }
    __syncthreads();
    if (tid == 0) {
        int off = 0, nt = 0;
        for (int e = 0; e < NE; e++) {
            soff[e] = off;
            for (int s = 0; s < sc[e]; s += 128) { ste[nt] = e; stm[nt] = s; nt++; }
            off += sc[e];
        }
        soff[NE] = off; snt = nt;
    }
    __syncthreads();
    int*   tok_list = meta + 256;
    float* w_list   = (float*)(meta + 8448);
    int*   posmap   = meta + 16640;
#pragma unroll
    for (int j = 0; j < TOPK; j++) {
        int e = e8[j];
        int p = soff[e] + atomicAdd(&scur[e], 1);
        tok_list[p] = tid;
        w_list[p]   = tkw[tid * TOPK + j];
        posmap[tid * TOPK + j] = p;
    }
    if (tid <= NE) meta[1 + tid] = soff[tid];
    if (tid == 0)  meta[0] = snt;
    if (tid < MAXT2) { meta[64 + tid] = (tid < snt) ? ste[tid] : 0;
                       meta[160 + tid] = (tid < snt) ? stm[tid] : 0; }
}

// GEMM1: A[row, c] = silu(gate)*up*w_row (bf16). 128 rows x 32 act cols/block.
// Reg-prefetch pipeline + double-buffered LDS, 1 sync per K-step.
__global__ __launch_bounds__(256) void k_mm1(
        const float* __restrict__ hs, const float* __restrict__ wgu,
        const int* __restrict__ meta, unsigned short* __restrict__ A) {
    // XCD-chunked swizzle (1536 blocks, 8 XCDs, 192/chunk; bijective since 1536%8==0)
    int lid = blockIdx.y * MAXT2 + blockIdx.x;
    int wsw = (lid & 7) * 192 + (lid >> 3);
    int bx = wsw % MAXT2, by = wsw / MAXT2;
    int numt = meta[0];
    if (bx >= numt) return;
    int e   = meta[64 + bx], m0 = meta[160 + bx];
    int seg = meta[1 + e];
    int nrows = meta[2 + e] - seg - m0;
    if (nrows > 128) nrows = 128;
    int c0 = by * 32;

    __shared__ __align__(16) unsigned short Xs[2][128][40];
    __shared__ __align__(16) unsigned short Ws[2][64][40];
    __shared__ int   toks[128];
    __shared__ float wrows[128];
    int tid = threadIdx.x;
    const int* tok_list = meta + 256;
    const float* w_list = (const float*)(meta + 8448);
    if (tid < 128) {
        toks[tid]  = (tid < nrows) ? tok_list[seg + m0 + tid] : -1;
        wrows[tid] = (tid < nrows) ? w_list[seg + m0 + tid] : 0.f;
    }
    __syncthreads();

    // per-thread staging slots (fixed across K)
    int xr1 = tid >> 2, xc = (tid & 3) * 8;
    int xr2 = xr1 + 64;
    int tk1 = toks[xr1], tk2 = toks[xr2];
    const float* xp1 = hs + (size_t)tk1 * HD + xc;
    const float* xp2 = hs + (size_t)tk2 * HD + xc;
    int wr = tid >> 2;                               // 0..63
    int wg_row = (wr < 32) ? (c0 + wr) : (FF + c0 + (wr - 32));
    const float* wp = wgu + (size_t)e * (2 * FF) * HD + (size_t)wg_row * HD + xc;

    int wave = tid >> 6, lane = tid & 63, lr = lane & 15, lk = lane >> 4;
    f32x4 accg[2][2] = {}, accu[2][2] = {};
    const float4 z4 = {0.f, 0.f, 0.f, 0.f};

    // prologue: stage k=0 into buffer 0
    {
        float4 a1 = tk1 >= 0 ? *(const float4*)(xp1)     : z4;
        float4 b1 = tk1 >= 0 ? *(const float4*)(xp1 + 4) : z4;
        float4 a2 = tk2 >= 0 ? *(const float4*)(xp2)     : z4;
        float4 b2 = tk2 >= 0 ? *(const float4*)(xp2 + 4) : z4;
        float4 wa = *(const float4*)(wp), wb = *(const float4*)(wp + 4);
        *(uint4*)&Xs[0][xr1][xc] = pk8v(a1, b1);
        *(uint4*)&Xs[0][xr2][xc] = pk8v(a2, b2);
        *(uint4*)&Ws[0][wr][xc]  = pk8v(wa, wb);
    }
    __syncthreads();

    int cur = 0;
    for (int k0 = 0; k0 < HD; k0 += 32) {
        bool more = (k0 + 32) < HD;
        float4 a1, b1, a2, b2, wa, wb;
        if (more) {                                   // issue next-step loads EARLY
            int k = k0 + 32;
            a1 = tk1 >= 0 ? *(const float4*)(xp1 + k)     : z4;
            b1 = tk1 >= 0 ? *(const float4*)(xp1 + k + 4) : z4;
            a2 = tk2 >= 0 ? *(const float4*)(xp2 + k)     : z4;
            b2 = tk2 >= 0 ? *(const float4*)(xp2 + k + 4) : z4;
            wa = *(const float4*)(wp + k);
            wb = *(const float4*)(wp + k + 4);
        }
        // compute current buffer (hides the in-flight loads)
        bf16x8 fa0 = *(const bf16x8*)&Xs[cur][wave * 32 + lr][lk * 8];
        bf16x8 fa1 = *(const bf16x8*)&Xs[cur][wave * 32 + 16 + lr][lk * 8];
#pragma unroll
        for (int cf = 0; cf < 2; cf++) {
            bf16x8 bg = *(const bf16x8*)&Ws[cur][cf * 16 + lr][lk * 8];
            bf16x8 bu = *(const bf16x8*)&Ws[cur][32 + cf * 16 + lr][lk * 8];
            accg[0][cf] = MFMA16(fa0, bg, accg[0][cf]);
            accg[1][cf] = MFMA16(fa1, bg, accg[1][cf]);
            accu[0][cf] = MFMA16(fa0, bu, accu[0][cf]);
            accu[1][cf] = MFMA16(fa1, bu, accu[1][cf]);
        }
        if (more) {                                   // cvt + write LATE, other buffer
            *(uint4*)&Xs[cur ^ 1][xr1][xc] = pk8v(a1, b1);
            *(uint4*)&Xs[cur ^ 1][xr2][xc] = pk8v(a2, b2);
            *(uint4*)&Ws[cur ^ 1][wr][xc]  = pk8v(wa, wb);
        }
        __syncthreads();
        cur ^= 1;
    }
#pragma unroll
    for (int rf = 0; rf < 2; rf++)
#pragma unroll
        for (int q = 0; q < 4; q++) {
            int r = wave * 32 + rf * 16 + lk * 4 + q;
            if (r < nrows) {
                float w = wrows[r];
#pragma unroll
                for (int cf = 0; cf < 2; cf++) {
                    float g = accg[rf][cf][q], u = accu[rf][cf][q];
                    float act = (g / (1.f + __expf(-g))) * u * w;
                    A[(size_t)(seg + m0 + r) * FF + c0 + cf * 16 + lr] = f2bf_rne(act);
                }
            }
        }
}

// GEMM2: O_rows[row, n] = A[row,:] . Wd[e][n,:]. 128 rows x 64 out cols/block.
__global__ __launch_bounds__(256) void k_mm2(
        const unsigned short* __restrict__ A, const float* __restrict__ wd,
        const int* __restrict__ meta, float* __restrict__ O) {
    int lid = blockIdx.y * MAXT2 + blockIdx.x;
    int wsw = (lid & 7) * 192 + (lid >> 3);
    int bx = wsw % MAXT2, by = wsw / MAXT2;
    int numt = meta[0];
    if (bx >= numt) return;
    int e   = meta[64 + bx], m0 = meta[160 + bx];
    int seg = meta[1 + e];
    int nrows = meta[2 + e] - seg - m0;
    if (nrows > 128) nrows = 128;
    int n0 = by * 64;

    __shared__ __align__(16) unsigned short Xs[2][128][40];
    __shared__ __align__(16) unsigned short Ws[2][64][40];
    int tid = threadIdx.x;
    int xr1 = tid >> 2, xc = (tid & 3) * 8;
    int xr2 = xr1 + 64;
    bool v1 = xr1 < nrows, v2 = xr2 < nrows;
    const unsigned short* ap1 = A + (size_t)(seg + m0 + xr1) * FF + xc;
    const unsigned short* ap2 = A + (size_t)(seg + m0 + xr2) * FF + xc;
    int wr = tid >> 2;
    const float* wp = wd + (size_t)e * HD * FF + (size_t)(n0 + wr) * FF + xc;

    int wave = tid >> 6, lane = tid & 63, lr = lane & 15, lk = lane >> 4;
    f32x4 acc[2][4] = {};
    const uint4  zu = {0u, 0u, 0u, 0u};

    {   // prologue k=0 -> buf0
        uint4 x1 = v1 ? *(const uint4*)(ap1) : zu;
        uint4 x2 = v2 ? *(const uint4*)(ap2) : zu;
        float4 wa = *(const float4*)(wp), wb = *(const float4*)(wp + 4);
        *(uint4*)&Xs[0][xr1][xc] = x1;
        *(uint4*)&Xs[0][xr2][xc] = x2;
        *(uint4*)&Ws[0][wr][xc]  = pk8v(wa, wb);
    }
    __syncthreads();

    int cur = 0;
    for (int k0 = 0; k0 < FF; k0 += 32) {
        bool more = (k0 + 32) < FF;
        uint4 x1, x2; float4 wa, wb;
        if (more) {
            int k = k0 + 32;
            x1 = v1 ? *(const uint4*)(ap1 + k) : zu;
            x2 = v2 ? *(const uint4*)(ap2 + k) : zu;
            wa = *(const float4*)(wp + k);
            wb = *(const float4*)(wp + k + 4);
        }
        bf16x8 fa0 = *(const bf16x8*)&Xs[cur][wave * 32 + lr][lk * 8];
        bf16x8 fa1 = *(const bf16x8*)&Xs[cur][wave * 32 + 16 + lr][lk * 8];
#pragma unroll
        for (int cf = 0; cf < 4; cf++) {
            bf16x8 b = *(const bf16x8*)&Ws[cur][cf * 16 + lr][lk * 8];
            acc[0][cf] = MFMA16(fa0, b, acc[0][cf]);
            acc[1][cf] = MFMA16(fa1, b, acc[1][cf]);
        }
        if (more) {
            *(uint4*)&Xs[cur ^ 1][xr1][xc] = x1;
            *(uint4*)&Xs[cur ^ 1][xr2][xc] = x2;
            *(uint4*)&Ws[cur ^ 1][wr][xc]  = pk8v(wa, wb);
        }
        __syncthreads();
        cur ^= 1;
    }
#pragma unroll
    for (int rf = 0; rf < 2; rf++)
#pragma unroll
        for (int q = 0; q < 4; q++) {
            int r = wave * 32 + rf * 16 + lk * 4 + q;
            if (r < nrows) {
#pragma unroll
                for (int cf = 0; cf < 4; cf++)
                    O[(size_t)(seg + m0 + r) * HD + n0 + cf * 16 + lr] = acc[rf][cf][q];
            }
        }
}

__global__ void k_reduce(const float* __restrict__ O, const int* __restrict__ posmap,
                         float* __restrict__ out) {
    int i = blockIdx.x * blockDim.x + threadIdx.x;   // over NT*HD/4
    int t = i >> 8, c4 = i & 255;
    float4 acc = make_float4(0.f, 0.f, 0.f, 0.f);
#pragma unroll
    for (int k = 0; k < TOPK; k++) {
        int p = posmap[t * TOPK + k];
        float4 v = ((const float4*)(O + (size_t)p * HD))[c4];
        acc.x += v.x; acc.y += v.y; acc.z += v.z; acc.w += v.w;
    }
    ((float4*)out)[i] = acc;
}

// ============================ launch ============================
extern "C" void kernel_launch(void* const* d_in, const int* in_sizes, int n_in,
                              void* d_out, int out_size, void* d_ws, size_t ws_size,
                              hipStream_t stream) {
    const float* hs  = (const float*)d_in[0];   // (T, H)
    const int*   idx = (const int*)  d_in[1];   // (T, K)
    const float* tkw = (const float*)d_in[2];   // (T, K)
    const float* wgu = (const float*)d_in[3];   // (E, 2F, H)
    const float* wd  = (const float*)d_in[4];   // (E, H, F)
    float* out = (float*)d_out;                 // (T, H)

    const size_t OFF_A = 128 * 1024;
    const size_t OFF_O = OFF_A + (size_t)NPAIR * FF * 2;   // +8MB

    char* ws = (char*)d_ws;
    int* meta = (int*)ws;
    unsigned short* A_bf = (unsigned short*)(ws + OFF_A);
    float* O_rows        = (float*)(ws + OFF_O);
    const int* posmap    = meta + 16640;

    k_route<<<1, 1024, 0, stream>>>(idx, tkw, meta);
    dim3 g1(MAXT2, FF / 32);    // 96 x 16
    k_mm1<<<g1, 256, 0, stream>>>(hs, wgu, meta, A_bf);
    dim3 g2(MAXT2, HD / 64);    // 96 x 16
    k_mm2<<<g2, 256, 0, stream>>>(A_bf, wd, meta, O_rows);
    k_reduce<<<NT * HD / 4 / 256, 256, 0, stream>>>(O_rows, posmap, out);
}

// Round 5
// 156.452 us; speedup vs baseline: 2.5138x; 2.5138x over previous
//
#include <hip/hip_runtime.h>
#include <hip/hip_bf16.h>

// E=32 experts, H=1024 hidden, F=512 ffn, T=1024 tokens, K=8 top-k.
#define NE     32
#define HD     1024
#define FF     512
#define NT     1024
#define TOPK   8
#define NPAIR  (NT * TOPK)      // 8192 routed (token,k) rows
#define MAXT2  96               // max 128-row tiles: 8192/128 + 32

typedef __attribute__((ext_vector_type(8))) short  bf16x8;
typedef __attribute__((ext_vector_type(4))) float  f32x4;

__device__ __forceinline__ unsigned short f2bf_rne(float f) {
    unsigned u = __float_as_uint(f);
    u += 0x7FFFu + ((u >> 16) & 1u);
    return (unsigned short)(u >> 16);
}
__device__ __forceinline__ unsigned pk2(float x, float y) {
    __hip_bfloat162 h = __float22bfloat162_rn(float2{x, y});
    union { __hip_bfloat162 h; unsigned u; } c;
    c.h = h;
    return c.u;
}
__device__ __forceinline__ uint4 pk8v(float4 a, float4 b) {
    uint4 r;
    r.x = pk2(a.x, a.y); r.y = pk2(a.z, a.w);
    r.z = pk2(b.x, b.y); r.w = pk2(b.z, b.w);
    return r;
}
// async global->LDS, 16B per lane; LDS dest = wave-uniform base + lane*16
__device__ __forceinline__ void gload16(const void* g, void* l) {
    __builtin_amdgcn_global_load_lds(
        (const __attribute__((address_space(1))) unsigned int*)g,
        (__attribute__((address_space(3))) unsigned int*)l, 16, 0, 0);
}
// 8 f32 (two swizzled 16B LDS reads) -> bf16x8 fragment
__device__ __forceinline__ bf16x8 pkfrag(const void* p0, const void* p1) {
    f32x4 a = *(const f32x4*)p0;
    f32x4 b = *(const f32x4*)p1;
    union { unsigned u[4]; bf16x8 v; } r;
    r.u[0] = pk2(a[0], a[1]); r.u[1] = pk2(a[2], a[3]);
    r.u[2] = pk2(b[0], b[1]); r.u[3] = pk2(b[2], b[3]);
    return r.v;
}
#define MFMA16(a, b, c) __builtin_amdgcn_mfma_f32_16x16x32_bf16(a, b, c, 0, 0, 0)

// ---------------- workspace layout ----------------
// meta ints: [0]=numt, [1..33]=offsets, [64..159]=tile_e, [160..255]=tile_m,
//            [256..]=tok_list(8192), w_list @ +8448, posmap @ +16640
// bytes: Xg bf16 @128K (8320x1024 rows, 17MB) | A_bf (8320x512, 8.5MB) | O_rows f32 (32MB)
#define OFF_XG (128u * 1024u)
#define OFF_AB (OFF_XG + 8320u * 2048u)
#define OFF_O  (OFF_AB + 8320u * 1024u)

__global__ __launch_bounds__(1024) void k_route(const int* __restrict__ idx,
                                                const float* __restrict__ tkw,
                                                int* __restrict__ meta) {
    __shared__ int sc[NE], scur[NE], soff[NE + 1];
    __shared__ int ste[MAXT2], stm[MAXT2], snt;
    int tid = threadIdx.x;                      // tid == token
    if (tid < NE) { sc[tid] = 0; scur[tid] = 0; }
    __syncthreads();
    int e8[TOPK];
#pragma unroll
    for (int j = 0; j < TOPK; j++) { e8[j] = idx[tid * TOPK + j]; atomicAdd(&sc[e8[j]], 1); }
    __syncthreads();
    if (tid == 0) {
        int off = 0, nt = 0;
        for (int e = 0; e < NE; e++) {
            soff[e] = off;
            for (int s = 0; s < sc[e]; s += 128) { ste[nt] = e; stm[nt] = s; nt++; }
            off += sc[e];
        }
        soff[NE] = off; snt = nt;
    }
    __syncthreads();
    int*   tok_list = meta + 256;
    float* w_list   = (float*)(meta + 8448);
    int*   posmap   = meta + 16640;
#pragma unroll
    for (int j = 0; j < TOPK; j++) {
        int e = e8[j];
        int p = soff[e] + atomicAdd(&scur[e], 1);
        tok_list[p] = tid;
        w_list[p]   = tkw[tid * TOPK + j];
        posmap[tid * TOPK + j] = p;
    }
    if (tid <= NE) meta[1 + tid] = soff[tid];
    if (tid == 0)  meta[0] = snt;
    if (tid < MAXT2) { meta[64 + tid] = (tid < snt) ? ste[tid] : 0;
                       meta[160 + tid] = (tid < snt) ? stm[tid] : 0; }
}

// Pre-gather hs into routed-order bf16 rows: Xg[p][:] = bf16(hs[tok[p]][:])
__global__ void k_gather(const float* __restrict__ hs, const int* __restrict__ meta,
                         unsigned short* __restrict__ Xg) {
    int i = blockIdx.x * blockDim.x + threadIdx.x;   // NPAIR*128 threads
    int p = i >> 7, c = (i & 127) << 3;
    int tok = meta[256 + p];
    float4 a = *(const float4*)(hs + (size_t)tok * HD + c);
    float4 b = *(const float4*)(hs + (size_t)tok * HD + c + 4);
    *(uint4*)(Xg + (size_t)p * HD + c) = pk8v(a, b);
}

// GEMM1: A[row, c] = silu(gate)*up*w_row (bf16). Tile 128 rows x 32 col-pairs.
// X: bf16 [128][32] LDS (gload_lds, swz ((L>>7)&3)<<4); W: f32 [64][32] LDS
// (gload_lds, swz ((L>>7)&7)<<4), cvt to bf16 on fragment read.
__global__ __launch_bounds__(256) void k_mm1(
        const unsigned short* __restrict__ Xg, const float* __restrict__ wgu,
        const int* __restrict__ meta, unsigned short* __restrict__ A) {
    int lid = blockIdx.y * MAXT2 + blockIdx.x;          // XCD-bijective swizzle
    int wsw = (lid & 7) * 192 + (lid >> 3);             // 1536 % 8 == 0
    int bx = wsw % MAXT2, by = wsw / MAXT2;
    int numt = meta[0];
    if (bx >= numt) return;
    int e   = meta[64 + bx], m0 = meta[160 + bx];
    int seg = meta[1 + e];
    int nrows = meta[2 + e] - seg - m0;
    if (nrows > 128) nrows = 128;
    int c0 = by * 32;

    __shared__ __align__(16) unsigned char Xs[2][8192];
    __shared__ __align__(16) unsigned char Ws[2][8192];
    __shared__ float wrows[128];
    int tid = threadIdx.x;
    const float* w_list = (const float*)(meta + 8448);
    if (tid < 128) wrows[tid] = (tid < nrows) ? w_list[seg + m0 + tid] : 0.f;

    int wave = tid >> 6, lane = tid & 63, lr = lane & 15, lk = lane >> 4;

    // staging sources (per lane), inverse-swizzled; 2 X + 2 W issues per wave
    const unsigned char* xsrc[2];
    const unsigned char* wsrc[2];
    unsigned ldsoff[2];
#pragma unroll
    for (int i = 0; i < 2; i++) {
        unsigned Lp = (unsigned)(wave * 2 + i) * 1024u + (unsigned)lane * 16u;
        ldsoff[i] = Lp;
        unsigned xr = Lp >> 6, xc = (Lp & 63u) ^ (((Lp >> 7) & 3u) << 4);
        xsrc[i] = (const unsigned char*)Xg + (size_t)(seg + m0 + xr) * (HD * 2) + xc;
        unsigned wr_ = Lp >> 7, wc = (Lp & 127u) ^ ((wr_ & 7u) << 4);
        unsigned grow = (wr_ < 32) ? (c0 + wr_) : (FF + c0 + (wr_ - 32));
        wsrc[i] = (const unsigned char*)wgu + ((size_t)e * (2 * FF) + grow) * (HD * 4) + wc;
    }
    // fragment read offsets (swizzled)
    unsigned aoff[2];
#pragma unroll
    for (int mf = 0; mf < 2; mf++) {
        unsigned row = wave * 32 + mf * 16 + lr;
        aoff[mf] = row * 64 + (((unsigned)lk * 16) ^ (((row >> 1) & 3u) << 4));
    }
    unsigned boff0[4], boff1[4];
#pragma unroll
    for (int nf = 0; nf < 4; nf++) {
        unsigned row = nf * 16 + lr;
        unsigned swz = (row & 7u) << 4;
        boff0[nf] = row * 128 + (((unsigned)lk * 32) ^ swz);
        boff1[nf] = row * 128 + (((unsigned)lk * 32 + 16) ^ swz);
    }

    f32x4 accg[2][2] = {}, accu[2][2] = {};
#pragma unroll
    for (int i = 0; i < 2; i++) {        // prologue: stage k-step 0 -> buf0
        gload16(xsrc[i], &Xs[0][ldsoff[i]]);
        gload16(wsrc[i], &Ws[0][ldsoff[i]]);
    }
    __syncthreads();

    int cur = 0;
    for (int t = 0; t < HD / 32; ++t) {
        if (t + 1 < HD / 32) {           // issue next-tile loads, drain at barrier
#pragma unroll
            for (int i = 0; i < 2; i++) {
                xsrc[i] += 64; wsrc[i] += 128;
                gload16(xsrc[i], &Xs[cur ^ 1][ldsoff[i]]);
                gload16(wsrc[i], &Ws[cur ^ 1][ldsoff[i]]);
            }
        }
        const unsigned char* xb = Xs[cur];
        const unsigned char* wb = Ws[cur];
        bf16x8 af0 = *(const bf16x8*)(xb + aoff[0]);
        bf16x8 af1 = *(const bf16x8*)(xb + aoff[1]);
#pragma unroll
        for (int j = 0; j < 2; j++) {
            bf16x8 bg = pkfrag(wb + boff0[j],     wb + boff1[j]);
            bf16x8 bu = pkfrag(wb + boff0[j + 2], wb + boff1[j + 2]);
            accg[0][j] = MFMA16(af0, bg, accg[0][j]);
            accg[1][j] = MFMA16(af1, bg, accg[1][j]);
            accu[0][j] = MFMA16(af0, bu, accu[0][j]);
            accu[1][j] = MFMA16(af1, bu, accu[1][j]);
        }
        __syncthreads();
        cur ^= 1;
    }
#pragma unroll
    for (int mf = 0; mf < 2; mf++)
#pragma unroll
        for (int q = 0; q < 4; q++) {
            int r = wave * 32 + mf * 16 + lk * 4 + q;
            if (r < nrows) {
                float w = wrows[r];
#pragma unroll
                for (int j = 0; j < 2; j++) {
                    float g = accg[mf][j][q], u = accu[mf][j][q];
                    float act = (g / (1.f + __expf(-g))) * u * w;
                    A[(size_t)(seg + m0 + r) * FF + c0 + j * 16 + lr] = f2bf_rne(act);
                }
            }
        }
}

// GEMM2: O_rows[row, n] = A[row,:] . Wd[e][n,:]. Tile 128 rows x 64 out cols.
__global__ __launch_bounds__(256) void k_mm2(
        const unsigned short* __restrict__ A, const float* __restrict__ wd,
        const int* __restrict__ meta, float* __restrict__ O) {
    int lid = blockIdx.y * MAXT2 + blockIdx.x;
    int wsw = (lid & 7) * 192 + (lid >> 3);
    int bx = wsw % MAXT2, by = wsw / MAXT2;
    int numt = meta[0];
    if (bx >= numt) return;
    int e   = meta[64 + bx], m0 = meta[160 + bx];
    int seg = meta[1 + e];
    int nrows = meta[2 + e] - seg - m0;
    if (nrows > 128) nrows = 128;
    int n0 = by * 64;

    __shared__ __align__(16) unsigned char Xs[2][8192];
    __shared__ __align__(16) unsigned char Ws[2][8192];
    int tid = threadIdx.x;
    int wave = tid >> 6, lane = tid & 63, lr = lane & 15, lk = lane >> 4;

    const unsigned char* xsrc[2];
    const unsigned char* wsrc[2];
    unsigned ldsoff[2];
#pragma unroll
    for (int i = 0; i < 2; i++) {
        unsigned Lp = (unsigned)(wave * 2 + i) * 1024u + (unsigned)lane * 16u;
        ldsoff[i] = Lp;
        unsigned xr = Lp >> 6, xc = (Lp & 63u) ^ (((Lp >> 7) & 3u) << 4);
        xsrc[i] = (const unsigned char*)A + (size_t)(seg + m0 + xr) * (FF * 2) + xc;
        unsigned wr_ = Lp >> 7, wc = (Lp & 127u) ^ ((wr_ & 7u) << 4);
        wsrc[i] = (const unsigned char*)wd + ((size_t)e * HD + n0 + wr_) * (FF * 4) + wc;
    }
    unsigned aoff[2];
#pragma unroll
    for (int mf = 0; mf < 2; mf++) {
        unsigned row = wave * 32 + mf * 16 + lr;
        aoff[mf] = row * 64 + (((unsigned)lk * 16) ^ (((row >> 1) & 3u) << 4));
    }
    unsigned boff0[4], boff1[4];
#pragma unroll
    for (int nf = 0; nf < 4; nf++) {
        unsigned row = nf * 16 + lr;
        unsigned swz = (row & 7u) << 4;
        boff0[nf] = row * 128 + (((unsigned)lk * 32) ^ swz);
        boff1[nf] = row * 128 + (((unsigned)lk * 32 + 16) ^ swz);
    }

    f32x4 acc[2][4] = {};
#pragma unroll
    for (int i = 0; i < 2; i++) {
        gload16(xsrc[i], &Xs[0][ldsoff[i]]);
        gload16(wsrc[i], &Ws[0][ldsoff[i]]);
    }
    __syncthreads();

    int cur = 0;
    for (int t = 0; t < FF / 32; ++t) {
        if (t + 1 < FF / 32) {
#pragma unroll
            for (int i = 0; i < 2; i++) {
                xsrc[i] += 64; wsrc[i] += 128;
                gload16(xsrc[i], &Xs[cur ^ 1][ldsoff[i]]);
                gload16(wsrc[i], &Ws[cur ^ 1][ldsoff[i]]);
            }
        }
        const unsigned char* xb = Xs[cur];
        const unsigned char* wb = Ws[cur];
        bf16x8 af0 = *(const bf16x8*)(xb + aoff[0]);
        bf16x8 af1 = *(const bf16x8*)(xb + aoff[1]);
#pragma unroll
        for (int nf = 0; nf < 4; nf++) {
            bf16x8 b = pkfrag(wb + boff0[nf], wb + boff1[nf]);
            acc[0][nf] = MFMA16(af0, b, acc[0][nf]);
            acc[1][nf] = MFMA16(af1, b, acc[1][nf]);
        }
        __syncthreads();
        cur ^= 1;
    }
#pragma unroll
    for (int mf = 0; mf < 2; mf++)
#pragma unroll
        for (int q = 0; q < 4; q++) {
            int r = wave * 32 + mf * 16 + lk * 4 + q;
            if (r < nrows) {
#pragma unroll
                for (int nf = 0; nf < 4; nf++)
                    O[(size_t)(seg + m0 + r) * HD + n0 + nf * 16 + lr] = acc[mf][nf][q];
            }
        }
}

__global__ void k_reduce(const float* __restrict__ O, const int* __restrict__ posmap,
                         float* __restrict__ out) {
    int i = blockIdx.x * blockDim.x + threadIdx.x;   // over NT*HD/4
    int t = i >> 8, c4 = i & 255;
    float4 acc = make_float4(0.f, 0.f, 0.f, 0.f);
#pragma unroll
    for (int k = 0; k < TOPK; k++) {
        int p = posmap[t * TOPK + k];
        float4 v = ((const float4*)(O + (size_t)p * HD))[c4];
        acc.x += v.x; acc.y += v.y; acc.z += v.z; acc.w += v.w;
    }
    ((float4*)out)[i] = acc;
}

// ============================ launch ============================
extern "C" void kernel_launch(void* const* d_in, const int* in_sizes, int n_in,
                              void* d_out, int out_size, void* d_ws, size_t ws_size,
                              hipStream_t stream) {
    const float* hs  = (const float*)d_in[0];   // (T, H)
    const int*   idx = (const int*)  d_in[1];   // (T, K)
    const float* tkw = (const float*)d_in[2];   // (T, K)
    const float* wgu = (const float*)d_in[3];   // (E, 2F, H)
    const float* wd  = (const float*)d_in[4];   // (E, H, F)
    float* out = (float*)d_out;                 // (T, H)

    char* ws = (char*)d_ws;
    int* meta = (int*)ws;
    unsigned short* Xg   = (unsigned short*)(ws + OFF_XG);
    unsigned short* A_bf = (unsigned short*)(ws + OFF_AB);
    float* O_rows        = (float*)(ws + OFF_O);
    const int* posmap    = meta + 16640;

    k_route<<<1, 1024, 0, stream>>>(idx, tkw, meta);
    k_gather<<<NPAIR * (HD / 8) / 256, 256, 0, stream>>>(hs, meta, Xg);
    dim3 g1(MAXT2, FF / 32);    // 96 x 16 = 1536 blocks
    k_mm1<<<g1, 256, 0, stream>>>(Xg, wgu, meta, A_bf);
    dim3 g2(MAXT2, HD / 64);    // 96 x 16 = 1536 blocks
    k_mm2<<<g2, 256, 0, stream>>>(A_bf, wd, meta, O_rows);
    k_reduce<<<NT * HD / 4 / 256, 256, 0, stream>>>(O_rows, posmap, out);
}